// Round 8
// baseline (101.027 us; speedup 1.0000x reference)
//
#include <hip/hip_runtime.h>

#define NROWS 2048
#define KDIM  768
#define L     40
#define KCH   6          // K-chunks per matrix (768 = 6 * 128)
#define KCSZ  128        // K per chunk
#define HN    (NROWS * L)   // 81920 floats per h matrix

// ---------------------------------------------------------------------------
// Kernel 1: partial projections, K split across blocks (R2/R3-verified).
// KEY PROPERTY (R6/R7 lesson): per-block W working set = 40o x 128k x 4B
// = 20 KB -> L1-RESIDENT; the o-loop re-reads it from L1 hot. Full-K
// variants (61-123 KB/block) stream-missed L1 at ~200cyc -> 40-99 us.
// grid (128 rowblocks, 6 kchunks, 2 matrices) = 1536 blocks = 6/CU,
// 24 waves/CU. block 256 = 16 rows x 16 segs.
// ---------------------------------------------------------------------------
__global__ __launch_bounds__(256) void k_proj(const float* __restrict__ x,
                                              const float* __restrict__ y,
                                              const float* __restrict__ W1,
                                              float* __restrict__ part) {
    const int kc    = blockIdx.y;
    const int which = blockIdx.z;
    const float* __restrict__ A = which ? y : x;
    const int tid = threadIdx.x;
    const int r   = tid >> 4;
    const int seg = tid & 15;
    const int row0 = blockIdx.x * 16;

    __shared__ float sh[16 * 688];

    const float* arow = A + (size_t)(row0 + r) * KDIM + kc * KCSZ;
    float4 a0 = *(const float4*)(arow + seg * 4);
    float4 a1 = *(const float4*)(arow + 64 + seg * 4);

    const float* wbase = W1 + (size_t)which * KDIM + kc * KCSZ;
#pragma unroll 8
    for (int o = 0; o < L; ++o) {
        const float* wrow = wbase + (size_t)o * (2 * KDIM);
        float4 w0 = *(const float4*)(wrow + seg * 4);
        float4 w1 = *(const float4*)(wrow + 64 + seg * 4);
        float s = a0.x * w0.x + a0.y * w0.y + a0.z * w0.z + a0.w * w0.w
                + a1.x * w1.x + a1.y * w1.y + a1.z * w1.z + a1.w * w1.w;
        sh[r * 688 + o * 17 + seg] = s;
    }
    __syncthreads();

    float* pout = part + (size_t)(kc * 2 + which) * HN + (size_t)row0 * L;
    for (int idx = tid; idx < 16 * L; idx += 256) {
        int rr = idx / L;
        int o  = idx - rr * L;
        float s = 0.f;
        int base = rr * 688 + o * 17;
#pragma unroll
        for (int q = 0; q < 16; ++q) s += sh[base + q];
        pout[idx] = s;
    }
}

// ---------------------------------------------------------------------------
// Kernel 1b: reduce the 6 K-chunk partials -> hxb (b1 folded in) and hy.
// (R5-verified; ~3 us, fully coalesced.)
// ---------------------------------------------------------------------------
__global__ __launch_bounds__(256) void k_red(const float* __restrict__ part,
                                             const float* __restrict__ b1,
                                             float* __restrict__ hxb,
                                             float* __restrict__ hy) {
    int gid = blockIdx.x * 256 + threadIdx.x;   // 0 .. 2*HN-1
    int which = gid / HN;
    int rem   = gid - which * HN;
    float s = 0.f;
#pragma unroll
    for (int kc = 0; kc < KCH; ++kc)
        s += part[(size_t)(kc * 2 + which) * HN + rem];
    if (!which) {
        s += b1[rem % L];
        hxb[rem] = s;
    } else {
        hy[rem] = s;
    }
}

// ---------------------------------------------------------------------------
// Kernel 2: pairwise sum of exp(T_ij - 1) + diagonal T0 sum.  (R5/R7-verified,
// ~9 us in budget fit -- untouched.)
// ---------------------------------------------------------------------------
#define BI 128
#define BJ 64
#define STRD 44

__global__ __launch_bounds__(512, 4) void k_pair(const float* __restrict__ hxb,
                                                 const float* __restrict__ hy,
                                                 const float* __restrict__ W2,
                                                 const float* __restrict__ b2p,
                                                 float* __restrict__ pairE,
                                                 float* __restrict__ pairT) {
    __shared__ float shy[BI * STRD];
    __shared__ float shx[BJ * STRD];
    __shared__ float sw2[STRD];
    __shared__ float red[16];

    const int tid = threadIdx.x;
    const int i0 = blockIdx.x * BI;
    const int j0 = blockIdx.y * BJ;

    for (int idx = tid; idx < BI * 10; idx += 512) {
        int rr = idx / 10, c = idx - rr * 10;
        float4 v = ((const float4*)(hy + (size_t)i0 * L))[idx];
        *(float4*)(shy + rr * STRD + c * 4) = v;
    }
    for (int idx = tid; idx < BJ * 10; idx += 512) {
        int rr = idx / 10, c = idx - rr * 10;
        float4 v = ((const float4*)(hxb + (size_t)j0 * L))[idx];
        *(float4*)(shx + rr * STRD + c * 4) = v;
    }
    if (tid < 10) ((float4*)sw2)[tid] = ((const float4*)W2)[tid];
    __syncthreads();

    const int tx = tid & 15, ty = tid >> 4;   // ty 0..31

    float acc[4][4];
#pragma unroll
    for (int u = 0; u < 4; ++u)
#pragma unroll
        for (int v = 0; v < 4; ++v) acc[u][v] = 0.f;

    float4 ayA[4], axA[4], wA4;
    float4 ayB[4], axB[4], wB4;

#define LOADF(AY, AX, W4, K4) do {                                          \
    W4 = *(const float4*)(sw2 + (K4) * 4);                                  \
    _Pragma("unroll") for (int u_ = 0; u_ < 4; ++u_)                        \
        AY[u_] = *(const float4*)(shy + (ty + 32 * u_) * STRD + (K4) * 4);  \
    _Pragma("unroll") for (int v_ = 0; v_ < 4; ++v_)                        \
        AX[v_] = *(const float4*)(shx + (tx + 16 * v_) * STRD + (K4) * 4);  \
} while (0)

#define FMAF(AY, AX, W4) do {                                               \
    _Pragma("unroll") for (int u_ = 0; u_ < 4; ++u_)                        \
    _Pragma("unroll") for (int v_ = 0; v_ < 4; ++v_) {                      \
        float t;                                                            \
        t = AY[u_].x + AX[v_].x; t = fmaxf(t, 0.f); acc[u_][v_] += t * W4.x;\
        t = AY[u_].y + AX[v_].y; t = fmaxf(t, 0.f); acc[u_][v_] += t * W4.y;\
        t = AY[u_].z + AX[v_].z; t = fmaxf(t, 0.f); acc[u_][v_] += t * W4.z;\
        t = AY[u_].w + AX[v_].w; t = fmaxf(t, 0.f); acc[u_][v_] += t * W4.w;\
    }                                                                       \
} while (0)

    LOADF(ayA, axA, wA4, 0);
    LOADF(ayB, axB, wB4, 1);
    FMAF(ayA, axA, wA4); LOADF(ayA, axA, wA4, 2);
    FMAF(ayB, axB, wB4); LOADF(ayB, axB, wB4, 3);
    FMAF(ayA, axA, wA4); LOADF(ayA, axA, wA4, 4);
    FMAF(ayB, axB, wB4); LOADF(ayB, axB, wB4, 5);
    FMAF(ayA, axA, wA4); LOADF(ayA, axA, wA4, 6);
    FMAF(ayB, axB, wB4); LOADF(ayB, axB, wB4, 7);
    FMAF(ayA, axA, wA4); LOADF(ayA, axA, wA4, 8);
    FMAF(ayB, axB, wB4); LOADF(ayB, axB, wB4, 9);
    FMAF(ayA, axA, wA4);
    FMAF(ayB, axB, wB4);

#undef LOADF
#undef FMAF

    const float b2v = b2p[0];
    const float c1  = b2v - 1.f;
    float sumE = 0.f, sumT = 0.f;
#pragma unroll
    for (int u = 0; u < 4; ++u)
#pragma unroll
        for (int v = 0; v < 4; ++v) {
            int gi = i0 + ty + 32 * u;
            int gj = j0 + tx + 16 * v;
            float val = acc[u][v];
            if (gi == gj) sumT += val + b2v;
            sumE += __expf(val + c1);
        }

#pragma unroll
    for (int off = 32; off > 0; off >>= 1) {
        sumE += __shfl_down(sumE, off);
        sumT += __shfl_down(sumT, off);
    }
    int wid = tid >> 6;                     // 0..7
    if ((tid & 63) == 0) { red[wid] = sumE; red[8 + wid] = sumT; }
    __syncthreads();
    if (tid == 0) {
        float e = 0.f, t = 0.f;
#pragma unroll
        for (int q = 0; q < 8; ++q) { e += red[q]; t += red[8 + q]; }
        int bid = blockIdx.y * gridDim.x + blockIdx.x;   // 0..511
        pairE[bid] = e;
        pairT[bid] = t;
    }
}

// ---------------------------------------------------------------------------
// Kernel 3: reduce 512 block-partials -> lower_bound.  (R5/R7-verified)
// ---------------------------------------------------------------------------
__global__ __launch_bounds__(512) void k_fin(const float* __restrict__ pairE,
                                             const float* __restrict__ pairT,
                                             float* __restrict__ out) {
    __shared__ float red[16];
    const int tid = threadIdx.x;
    float e = pairE[tid];
    float t = pairT[tid];
#pragma unroll
    for (int off = 32; off > 0; off >>= 1) {
        e += __shfl_down(e, off);
        t += __shfl_down(t, off);
    }
    int wid = tid >> 6;
    if ((tid & 63) == 0) { red[wid] = e; red[8 + wid] = t; }
    __syncthreads();
    if (tid == 0) {
        float se = 0.f, st = 0.f;
#pragma unroll
        for (int q = 0; q < 8; ++q) { se += red[q]; st += red[8 + q]; }
        const float invN = 1.0f / (float)NROWS;
        out[0] = st * invN - se * invN * invN;
    }
}

extern "C" void kernel_launch(void* const* d_in, const int* in_sizes, int n_in,
                              void* d_out, int out_size, void* d_ws, size_t ws_size,
                              hipStream_t stream) {
    const float* x  = (const float*)d_in[0];
    const float* y  = (const float*)d_in[1];
    const float* W1 = (const float*)d_in[2];
    const float* b1 = (const float*)d_in[3];
    const float* W2 = (const float*)d_in[4];
    const float* b2 = (const float*)d_in[5];
    float* out = (float*)d_out;

    float* wsf   = (float*)d_ws;
    float* hxb   = wsf;                  // 2048*40, b1 folded in
    float* hy    = hxb + HN;             // 2048*40
    float* part  = hy + HN;              // 6*2*2048*40 partials
    float* pairE = part + (size_t)KCH * 2 * HN;   // 512
    float* pairT = pairE + 512;                   // 512

    k_proj<<<dim3(NROWS / 16, KCH, 2), 256, 0, stream>>>(x, y, W1, part);
    k_red<<<(2 * HN) / 256, 256, 0, stream>>>(part, b1, hxb, hy);
    k_pair<<<dim3(NROWS / BI, NROWS / BJ), 512, 0, stream>>>(hxb, hy, W2, b2, pairE, pairT);
    k_fin<<<1, 512, 0, stream>>>(pairE, pairT, out);
}

// Round 9
// 95.850 us; speedup vs baseline: 1.0540x; 1.0540x over previous
//
#include <hip/hip_runtime.h>

#define NROWS 2048
#define KDIM  768
#define L     40
#define HN    (NROWS * L)   // 81920 floats per h matrix

#define OPB   10    // o per block (40 / 4 o-groups)
#define RPB   32    // rows per block
#define WF4   192   // float4 per staged W row (768 floats)

// ---------------------------------------------------------------------------
// Kernel 1: projection with W TILE IN LDS (the fix for the ~37us k_proj).
// R1-R8 lesson: every reg/L1-based variant hit 35-45us because W reuse went
// through L2 (6 blocks x 20KB thrashed the 32KB L1 -> ~1.9MB L2 traffic/CU).
// Here: W tile (10 o x 768 k = 30KB) staged to LDS ONCE per block; inner
// loop = ds_read_b128 broadcast (2 unique addrs/wave = conflict-free) + FMA
// with A in registers (3-chunk explicit double-buffer, static names).
// o-split => no K-partials => no k_red kernel. grid (64,4,2)=512 = 2/CU.
// ---------------------------------------------------------------------------
__global__ __launch_bounds__(256) void k_proj(const float* __restrict__ x,
                                              const float* __restrict__ y,
                                              const float* __restrict__ W1,
                                              const float* __restrict__ b1,
                                              float* __restrict__ hxb,
                                              float* __restrict__ hy) {
    const int og    = blockIdx.y;        // 0..3 -> o range [og*10, og*10+10)
    const int which = blockIdx.z;
    const float* __restrict__ A = which ? y : x;
    const int tid = threadIdx.x;
    const int r   = tid & 31;            // 0..31 row within block
    const int s   = tid >> 5;            // 0..7 k-segment (96 k each)
    const int row0 = blockIdx.x * RPB;
    const int o0   = og * OPB;

    __shared__ float4 wlds[OPB * WF4];   // 30 KB: [10 o][192 f4]

    // ---- stage W tile (cooperative, linear f4 writes) ----
    const float4* W1f4 = (const float4*)W1;          // 384 f4 per W1 row
    for (int i = tid; i < OPB * WF4; i += 256) {
        int ol = i / WF4, q = i - ol * WF4;
        wlds[ol * WF4 + q] = W1f4[(size_t)(o0 + ol) * 384 + which * WF4 + q];
    }

    // ---- A pointers: this thread's row, kseg s covers k [s*96, s*96+96) ----
    const float4* arow = (const float4*)(A + (size_t)(row0 + r) * KDIM) + s * 24;

    float acc[OPB];
#pragma unroll
    for (int ol = 0; ol < OPB; ++ol) acc[ol] = 0.f;

    float4 aA[8], aB[8];
#pragma unroll
    for (int j = 0; j < 8; ++j) aA[j] = arow[j];     // chunk 0 (overlaps staging)
    __syncthreads();                                  // W tile ready

#define COMPUTE(AR, C) do {                                                  \
    _Pragma("unroll") for (int ol = 0; ol < OPB; ++ol) {                     \
        const float4* wp = &wlds[ol * WF4 + s * 24 + (C) * 8];               \
        float sacc = 0.f;                                                    \
        _Pragma("unroll") for (int j = 0; j < 8; ++j) {                      \
            float4 w = wp[j];                                                \
            sacc += AR[j].x * w.x + AR[j].y * w.y                            \
                  + AR[j].z * w.z + AR[j].w * w.w;                           \
        }                                                                    \
        acc[ol] += sacc;                                                     \
    } } while (0)

#pragma unroll
    for (int j = 0; j < 8; ++j) aB[j] = arow[8 + j]; // prefetch chunk 1
    COMPUTE(aA, 0);
#pragma unroll
    for (int j = 0; j < 8; ++j) aA[j] = arow[16 + j];// prefetch chunk 2
    COMPUTE(aB, 1);
    COMPUTE(aA, 2);
#undef COMPUTE

    // ---- cross-kseg reduce via LDS (reuse W area after sync) ----
    __syncthreads();
    float* red = (float*)wlds;                       // needs 2560 floats
#pragma unroll
    for (int ol = 0; ol < OPB; ++ol)
        red[(ol * 8 + s) * 32 + r] = acc[ol];        // bank = r -> conflict-free
    __syncthreads();

    for (int idx = tid; idx < RPB * OPB; idx += 256) {
        int rr = idx / OPB, ol = idx - rr * OPB;
        float v = 0.f;
#pragma unroll
        for (int ss = 0; ss < 8; ++ss)
            v += red[(ol * 8 + ss) * 32 + rr];
        int o = o0 + ol;
        if (!which) {
            hxb[(size_t)(row0 + rr) * L + o] = v + b1[o];
        } else {
            hy[(size_t)(row0 + rr) * L + o] = v;
        }
    }
}

// ---------------------------------------------------------------------------
// Kernel 2: pairwise sum of exp(T_ij - 1) + diagonal T0 sum.  (R5/R7/R8-
// verified, ~9 us budget-fit -- untouched.)
// ---------------------------------------------------------------------------
#define BI 128
#define BJ 64
#define STRD 44

__global__ __launch_bounds__(512, 4) void k_pair(const float* __restrict__ hxb,
                                                 const float* __restrict__ hy,
                                                 const float* __restrict__ W2,
                                                 const float* __restrict__ b2p,
                                                 float* __restrict__ pairE,
                                                 float* __restrict__ pairT) {
    __shared__ float shy[BI * STRD];
    __shared__ float shx[BJ * STRD];
    __shared__ float sw2[STRD];
    __shared__ float red[16];

    const int tid = threadIdx.x;
    const int i0 = blockIdx.x * BI;
    const int j0 = blockIdx.y * BJ;

    for (int idx = tid; idx < BI * 10; idx += 512) {
        int rr = idx / 10, c = idx - rr * 10;
        float4 v = ((const float4*)(hy + (size_t)i0 * L))[idx];
        *(float4*)(shy + rr * STRD + c * 4) = v;
    }
    for (int idx = tid; idx < BJ * 10; idx += 512) {
        int rr = idx / 10, c = idx - rr * 10;
        float4 v = ((const float4*)(hxb + (size_t)j0 * L))[idx];
        *(float4*)(shx + rr * STRD + c * 4) = v;
    }
    if (tid < 10) ((float4*)sw2)[tid] = ((const float4*)W2)[tid];
    __syncthreads();

    const int tx = tid & 15, ty = tid >> 4;   // ty 0..31

    float acc[4][4];
#pragma unroll
    for (int u = 0; u < 4; ++u)
#pragma unroll
        for (int v = 0; v < 4; ++v) acc[u][v] = 0.f;

    float4 ayA[4], axA[4], wA4;
    float4 ayB[4], axB[4], wB4;

#define LOADF(AY, AX, W4, K4) do {                                          \
    W4 = *(const float4*)(sw2 + (K4) * 4);                                  \
    _Pragma("unroll") for (int u_ = 0; u_ < 4; ++u_)                        \
        AY[u_] = *(const float4*)(shy + (ty + 32 * u_) * STRD + (K4) * 4);  \
    _Pragma("unroll") for (int v_ = 0; v_ < 4; ++v_)                        \
        AX[v_] = *(const float4*)(shx + (tx + 16 * v_) * STRD + (K4) * 4);  \
} while (0)

#define FMAF(AY, AX, W4) do {                                               \
    _Pragma("unroll") for (int u_ = 0; u_ < 4; ++u_)                        \
    _Pragma("unroll") for (int v_ = 0; v_ < 4; ++v_) {                      \
        float t;                                                            \
        t = AY[u_].x + AX[v_].x; t = fmaxf(t, 0.f); acc[u_][v_] += t * W4.x;\
        t = AY[u_].y + AX[v_].y; t = fmaxf(t, 0.f); acc[u_][v_] += t * W4.y;\
        t = AY[u_].z + AX[v_].z; t = fmaxf(t, 0.f); acc[u_][v_] += t * W4.z;\
        t = AY[u_].w + AX[v_].w; t = fmaxf(t, 0.f); acc[u_][v_] += t * W4.w;\
    }                                                                       \
} while (0)

    LOADF(ayA, axA, wA4, 0);
    LOADF(ayB, axB, wB4, 1);
    FMAF(ayA, axA, wA4); LOADF(ayA, axA, wA4, 2);
    FMAF(ayB, axB, wB4); LOADF(ayB, axB, wB4, 3);
    FMAF(ayA, axA, wA4); LOADF(ayA, axA, wA4, 4);
    FMAF(ayB, axB, wB4); LOADF(ayB, axB, wB4, 5);
    FMAF(ayA, axA, wA4); LOADF(ayA, axA, wA4, 6);
    FMAF(ayB, axB, wB4); LOADF(ayB, axB, wB4, 7);
    FMAF(ayA, axA, wA4); LOADF(ayA, axA, wA4, 8);
    FMAF(ayB, axB, wB4); LOADF(ayB, axB, wB4, 9);
    FMAF(ayA, axA, wA4);
    FMAF(ayB, axB, wB4);

#undef LOADF
#undef FMAF

    const float b2v = b2p[0];
    const float c1  = b2v - 1.f;
    float sumE = 0.f, sumT = 0.f;
#pragma unroll
    for (int u = 0; u < 4; ++u)
#pragma unroll
        for (int v = 0; v < 4; ++v) {
            int gi = i0 + ty + 32 * u;
            int gj = j0 + tx + 16 * v;
            float val = acc[u][v];
            if (gi == gj) sumT += val + b2v;
            sumE += __expf(val + c1);
        }

#pragma unroll
    for (int off = 32; off > 0; off >>= 1) {
        sumE += __shfl_down(sumE, off);
        sumT += __shfl_down(sumT, off);
    }
    int wid = tid >> 6;                     // 0..7
    if ((tid & 63) == 0) { red[wid] = sumE; red[8 + wid] = sumT; }
    __syncthreads();
    if (tid == 0) {
        float e = 0.f, t = 0.f;
#pragma unroll
        for (int q = 0; q < 8; ++q) { e += red[q]; t += red[8 + q]; }
        int bid = blockIdx.y * gridDim.x + blockIdx.x;   // 0..511
        pairE[bid] = e;
        pairT[bid] = t;
    }
}

// ---------------------------------------------------------------------------
// Kernel 3: reduce 512 block-partials -> lower_bound.  (verified)
// ---------------------------------------------------------------------------
__global__ __launch_bounds__(512) void k_fin(const float* __restrict__ pairE,
                                             const float* __restrict__ pairT,
                                             float* __restrict__ out) {
    __shared__ float red[16];
    const int tid = threadIdx.x;
    float e = pairE[tid];
    float t = pairT[tid];
#pragma unroll
    for (int off = 32; off > 0; off >>= 1) {
        e += __shfl_down(e, off);
        t += __shfl_down(t, off);
    }
    int wid = tid >> 6;
    if ((tid & 63) == 0) { red[wid] = e; red[8 + wid] = t; }
    __syncthreads();
    if (tid == 0) {
        float se = 0.f, st = 0.f;
#pragma unroll
        for (int q = 0; q < 8; ++q) { se += red[q]; st += red[8 + q]; }
        const float invN = 1.0f / (float)NROWS;
        out[0] = st * invN - se * invN * invN;
    }
}

extern "C" void kernel_launch(void* const* d_in, const int* in_sizes, int n_in,
                              void* d_out, int out_size, void* d_ws, size_t ws_size,
                              hipStream_t stream) {
    const float* x  = (const float*)d_in[0];
    const float* y  = (const float*)d_in[1];
    const float* W1 = (const float*)d_in[2];
    const float* b1 = (const float*)d_in[3];
    const float* W2 = (const float*)d_in[4];
    const float* b2 = (const float*)d_in[5];
    float* out = (float*)d_out;

    float* wsf   = (float*)d_ws;
    float* hxb   = wsf;                  // 2048*40, b1 folded in
    float* hy    = hxb + HN;             // 2048*40
    float* pairE = hy + HN;              // 512
    float* pairT = pairE + 512;          // 512

    k_proj<<<dim3(NROWS / RPB, 4, 2), 256, 0, stream>>>(x, y, W1, b1, hxb, hy);
    k_pair<<<dim3(NROWS / BI, NROWS / BJ), 512, 0, stream>>>(hxb, hy, W2, b2, pairE, pairT);
    k_fin<<<1, 512, 0, stream>>>(pairE, pairT, out);
}